// Round 1
// baseline (260.789 us; speedup 1.0000x reference)
//
#include <hip/hip_runtime.h>

#define EPSF 1e-8f

// ---------- small helpers ----------
__device__ __forceinline__ float4 f4add(float4 a, float4 b){
  return make_float4(a.x+b.x, a.y+b.y, a.z+b.z, a.w+b.w);
}
__device__ __forceinline__ float4 f4scale(float4 a, float s){
  return make_float4(a.x*s, a.y*s, a.z*s, a.w*s);
}
__device__ __forceinline__ float f4dot(float4 a, float4 b){
  return a.x*b.x + a.y*b.y + a.z*b.z + a.w*b.w;
}
__device__ __forceinline__ float wave_sum(float v){
  #pragma unroll
  for (int off = 32; off > 0; off >>= 1) v += __shfl_down(v, off);
  return v;  // valid on lane 0
}

// Dimensions (compile-time constants)
#define B_  32
#define C_  16
#define L_  128
#define D_  768
#define D4_ 192   // D/4
#define P_  196
#define OM_ 10
#define OE_ 10
#define R_  36

// ---------- generic split-K mean (partial) ----------
// in: [N, ROWS, 768]; grid = N*CH blocks of 192 threads; thread t = float4 col.
// part: [N*CH, 768]; msum (if mask): [N*CH]
__global__ __launch_bounds__(192)
void mean_partial_k(const float* __restrict__ in, const float* __restrict__ mask,
                    float* __restrict__ part, float* __restrict__ msum,
                    int ROWS, int CH, int RPC)
{
  int blk = blockIdx.x;
  int g = blk / CH, ch = blk - g * CH;
  int r0 = ch * RPC;
  int r1 = r0 + RPC; if (r1 > ROWS) r1 = ROWS;
  int t = threadIdx.x;
  const float4* inp = (const float4*)in + (size_t)g * ROWS * D4_;
  float4 acc = make_float4(0.f, 0.f, 0.f, 0.f);
  if (mask) {
    const float* mrow = mask + (size_t)g * ROWS;
    float ms = 0.f;
    for (int r = r0; r < r1; ++r) {
      float w = mrow[r];
      float4 v = inp[(size_t)r * D4_ + t];
      acc.x += v.x * w; acc.y += v.y * w; acc.z += v.z * w; acc.w += v.w * w;
      ms += w;
    }
    if (t == 0) msum[blk] = ms;
  } else {
    #pragma unroll 4
    for (int r = r0; r < r1; ++r)
      acc = f4add(acc, inp[(size_t)r * D4_ + t]);
  }
  ((float4*)part)[(size_t)blk * D4_ + t] = acc;
}

// out[g,768] = sum_ch part / denom ; denom = max(sum msum,1) if masked else 1/invn given
__global__ void mean_combine_k(const float* __restrict__ part, const float* __restrict__ msum,
                               float* __restrict__ out, int N, int CH, float invn)
{
  int idx = blockIdx.x * blockDim.x + threadIdx.x;
  if (idx >= N * D4_) return;
  int g = idx / D4_, t = idx - g * D4_;
  const float4* pp = (const float4*)part + (size_t)g * CH * D4_ + t;
  float4 acc = make_float4(0.f, 0.f, 0.f, 0.f);
  for (int ch = 0; ch < CH; ++ch) acc = f4add(acc, pp[(size_t)ch * D4_]);
  float scale;
  if (msum) {
    float s = 0.f;
    for (int ch = 0; ch < CH; ++ch) s += msum[g * CH + ch];
    scale = 1.f / fmaxf(s, 1.f);
  } else scale = invn;
  ((float4*)out)[idx] = f4scale(acc, scale);
}

// ---------- span gather: m_span = 0.5*(mtf[b,sp]+mtf[b,ep]) ----------
__global__ void span_k(const float* __restrict__ mtf, const int* __restrict__ sp,
                       const int* __restrict__ ep, float* __restrict__ m_span)
{
  int idx = blockIdx.x * blockDim.x + threadIdx.x;  // B*192
  if (idx >= B_ * D4_) return;
  int b = idx / D4_, t = idx - b * D4_;
  const float4* base = (const float4*)mtf + (size_t)b * L_ * D4_;
  float4 a = base[(size_t)sp[b] * D4_ + t];
  float4 c = base[(size_t)ep[b] * D4_ + t];
  ((float4*)m_span)[idx] = f4scale(f4add(a, c), 0.5f);
}

// ---------- q[b,i] = mos[b,i]/max(|m_mean[b,i]|,eps) ; wave per (b,i) ----------
__global__ void norm_q_k(const float* __restrict__ m_mean, const float* __restrict__ mos,
                         float* __restrict__ q)
{
  int w = (blockIdx.x * blockDim.x + threadIdx.x) >> 6;
  int lane = threadIdx.x & 63;
  if (w >= B_ * OM_) return;
  const float4* mp = (const float4*)m_mean + (size_t)w * D4_;
  float n = 0.f;
  #pragma unroll
  for (int k = 0; k < 3; ++k) { float4 v = mp[lane + 64 * k]; n += f4dot(v, v); }
  n = wave_sum(n);
  if (lane == 0) q[w] = mos[w] / fmaxf(sqrtf(n), EPSF);
}

// ---------- mtet[b,c] = cos(m_span[b], etf[b,c,0,:]) ; wave per (b,c) ----------
__global__ void mtet_k(const float* __restrict__ etf, const float* __restrict__ m_span,
                       float* __restrict__ mtet)
{
  int w = (blockIdx.x * blockDim.x + threadIdx.x) >> 6;
  int lane = threadIdx.x & 63;
  if (w >= B_ * C_) return;
  int b = w / C_;
  const float4* ecls = (const float4*)etf + (size_t)w * L_ * D4_;  // l = 0
  const float4* ms   = (const float4*)m_span + (size_t)b * D4_;
  float dt = 0.f, na = 0.f, nb = 0.f;
  #pragma unroll
  for (int k = 0; k < 3; ++k) {
    float4 a = ms[lane + 64 * k];
    float4 e = ecls[lane + 64 * k];
    dt += f4dot(a, e); na += f4dot(a, a); nb += f4dot(e, e);
  }
  dt = wave_sum(dt); na = wave_sum(na); nb = wave_sum(nb);
  if (lane == 0) mtet[w] = dt / fmaxf(sqrtf(na) * sqrtf(nb), EPSF);
}

// ---------- eof fused: mean over R, norm, dot vs all m ----------
// grid: B*C*5 blocks x 128 threads (2 waves, wave handles j = jp*2+waveid)
// p[b,c,j] = eos * (1/max(|e|,eps)) * sum_i q[b,i]*(m[b,i]·e[b,c,j])
__global__ __launch_bounds__(128)
void eof_dot_k(const float* __restrict__ eof, const float* __restrict__ m_mean,
               const float* __restrict__ q, const float* __restrict__ eos,
               float* __restrict__ p)
{
  int blk = blockIdx.x;          // (b*C + c)*5 + jp
  int bc = blk / 5, jp = blk - bc * 5;
  int b = bc / C_;
  int wave = threadIdx.x >> 6, lane = threadIdx.x & 63;
  int j = jp * 2 + wave;
  size_t g = (size_t)bc * OE_ + j;
  const float4* ep = (const float4*)eof + g * R_ * D4_;
  float4 a0 = make_float4(0,0,0,0), a1 = a0, a2 = a0;
  #pragma unroll 4
  for (int r = 0; r < R_; ++r) {
    const float4* row = ep + (size_t)r * D4_;
    a0 = f4add(a0, row[lane]);
    a1 = f4add(a1, row[lane + 64]);
    a2 = f4add(a2, row[lane + 128]);
  }
  const float inv36 = 1.f / 36.f;
  a0 = f4scale(a0, inv36); a1 = f4scale(a1, inv36); a2 = f4scale(a2, inv36);
  float nrm = f4dot(a0, a0) + f4dot(a1, a1) + f4dot(a2, a2);
  float s = 0.f;
  const float4* mp = (const float4*)m_mean + (size_t)b * OM_ * D4_;
  #pragma unroll
  for (int i = 0; i < OM_; ++i) {
    const float4* mr = mp + (size_t)i * D4_;
    float di = f4dot(a0, mr[lane]) + f4dot(a1, mr[lane + 64]) + f4dot(a2, mr[lane + 128]);
    s += q[b * OM_ + i] * di;
  }
  s = wave_sum(s); nrm = wave_sum(nrm);
  if (lane == 0) {
    float einv = 1.f / fmaxf(sqrtf(nrm), EPSF);
    p[g] = eos[g] * s * einv;
  }
}

// ---------- miei[b,c] = sum_j p / (sum_i mos * sum_j eos) ----------
__global__ void miei_k(const float* __restrict__ p, const float* __restrict__ mos,
                       const float* __restrict__ eos, float* __restrict__ miei)
{
  int bc = blockIdx.x * blockDim.x + threadIdx.x;
  if (bc >= B_ * C_) return;
  int b = bc / C_;
  float num = 0.f, se = 0.f, sm = 0.f;
  #pragma unroll
  for (int j = 0; j < OE_; ++j) { num += p[bc * OE_ + j]; se += eos[bc * OE_ + j]; }
  #pragma unroll
  for (int i = 0; i < OM_; ++i) sm += mos[b * OM_ + i];
  miei[bc] = num / (sm * se);
}

// ---------- GCN (2 layers collapsed) -> mention[B,D], s[B,D] ----------
// entity[b,c,d] = v_et[b,c,d] * s[b,d]
__global__ void gcn_k(const float* __restrict__ v_mt, const float* __restrict__ v_mi,
                      const float* __restrict__ v_et, const float* __restrict__ v_ei,
                      const float* __restrict__ mtet, const float* __restrict__ mtei,
                      const float* __restrict__ miet, const float* __restrict__ miei,
                      float* __restrict__ mention, float* __restrict__ s_out)
{
  int idx = blockIdx.x * blockDim.x + threadIdx.x;  // B*768
  if (idx >= B_ * D_) return;
  int b = idx / D_, d = idx - b * D_;
  float vmt = v_mt[idx], vmi = v_mi[idx];
  float nv0 = 0.f, nv1 = 0.f, macc = 0.f;
  #pragma unroll
  for (int c = 0; c < C_; ++c) {
    int bc = b * C_ + c;
    float et = v_et[(size_t)bc * D_ + d];
    float ei = v_ei[(size_t)bc * D_ + d];
    float e0 = mtet[bc], e1 = mtei[bc], e2 = miet[bc], e3 = miei[bc];
    nv0 += e0 * et + e1 * ei;               // layer1 vertex0 (x16 mean later)
    nv1 += e2 * et + e3 * ei;               // layer1 vertex1
    // layer2 mention accum: nE0*nv2 + nE1*nv3
    macc += (vmt * et) * (e0 * vmt + e2 * vmi)
          + (vmt * ei) * (e1 * vmt + e3 * vmi);
  }
  const float invC = 1.f / (float)C_;
  nv0 *= invC; nv1 *= invC;
  mention[idx] = macc * invC;
  s_out[idx] = vmt * nv0 + vmi * nv1;
}

// ---------- final: out[b,c] = cos(mention[b], v_et[b,c]*s[b]) ; wave per (b,c) ----------
__global__ void final_k(const float* __restrict__ mention, const float* __restrict__ s,
                        const float* __restrict__ v_et, float* __restrict__ out)
{
  int w = (blockIdx.x * blockDim.x + threadIdx.x) >> 6;
  int lane = threadIdx.x & 63;
  if (w >= B_ * C_) return;
  int b = w / C_;
  const float4* mp = (const float4*)mention + (size_t)b * D4_;
  const float4* sp = (const float4*)s + (size_t)b * D4_;
  const float4* ep = (const float4*)v_et + (size_t)w * D4_;
  float dt = 0.f, nm = 0.f, ne = 0.f;
  #pragma unroll
  for (int k = 0; k < 3; ++k) {
    float4 m = mp[lane + 64 * k];
    float4 sv = sp[lane + 64 * k];
    float4 e = ep[lane + 64 * k];
    float4 ent = make_float4(e.x * sv.x, e.y * sv.y, e.z * sv.z, e.w * sv.w);
    dt += f4dot(m, ent); nm += f4dot(m, m); ne += f4dot(ent, ent);
  }
  dt = wave_sum(dt); nm = wave_sum(nm); ne = wave_sum(ne);
  if (lane == 0) out[w] = dt / fmaxf(sqrtf(nm) * sqrtf(ne), EPSF);
}

extern "C" void kernel_launch(void* const* d_in, const int* in_sizes, int n_in,
                              void* d_out, int out_size, void* d_ws, size_t ws_size,
                              hipStream_t stream)
{
  const float* mtf  = (const float*)d_in[0];
  const float* mtm  = (const float*)d_in[1];
  const int*   msp  = (const int*)  d_in[2];
  const int*   mep  = (const int*)  d_in[3];
  const float* mif  = (const float*)d_in[4];
  const float* mof  = (const float*)d_in[5];
  const float* mos  = (const float*)d_in[6];
  const float* etf  = (const float*)d_in[7];
  const float* etm  = (const float*)d_in[8];
  const float* eif  = (const float*)d_in[9];
  const float* eofp = (const float*)d_in[10];
  const float* eos  = (const float*)d_in[11];
  const float* miet = (const float*)d_in[12];
  const float* mtei = (const float*)d_in[13];
  float* out = (float*)d_out;
  float* ws = (float*)d_ws;

  // workspace layout (floats)
  float* PART    = ws;                    // 2752512 (max partial: eif 512*7*768)
  float* MSUM    = PART    + 2752512;     // 8192
  float* V_MT    = MSUM    + 8192;        // 24576
  float* V_MI    = V_MT    + 24576;       // 24576
  float* V_ET    = V_MI    + 24576;       // 393216
  float* V_EI    = V_ET    + 393216;      // 393216
  float* M_MEAN  = V_EI    + 393216;      // 245760
  float* M_SPAN  = M_MEAN  + 245760;      // 24576
  float* Q       = M_SPAN  + 24576;       // 320
  float* MTET    = Q       + 320;         // 512
  float* MIEI    = MTET    + 512;         // 512
  float* P_BUF   = MIEI    + 512;         // 5120
  float* MENTION = P_BUF   + 5120;        // 24576
  float* S_ARR   = MENTION + 24576;       // 24576

  // --- mtf -> v_mt (masked mean over L=128), CH=16 (8 rows each) ---
  mean_partial_k<<<32 * 16, 192, 0, stream>>>(mtf, mtm, PART, MSUM, 128, 16, 8);
  mean_combine_k<<<24, 256, 0, stream>>>(PART, MSUM, V_MT, 32, 16, 0.f);

  // --- m_span gather ---
  span_k<<<24, 256, 0, stream>>>(mtf, msp, mep, M_SPAN);

  // --- mif -> v_mi (mean over P=196), CH=28 (7 rows each) ---
  mean_partial_k<<<32 * 28, 192, 0, stream>>>(mif, nullptr, PART, nullptr, 196, 28, 7);
  mean_combine_k<<<24, 256, 0, stream>>>(PART, nullptr, V_MI, 32, 28, 1.f / 196.f);

  // --- mof -> m_mean (mean over R=36), CH=6 (6 rows each) ---
  mean_partial_k<<<320 * 6, 192, 0, stream>>>(mof, nullptr, PART, nullptr, 36, 6, 6);
  mean_combine_k<<<240, 256, 0, stream>>>(PART, nullptr, M_MEAN, 320, 6, 1.f / 36.f);
  norm_q_k<<<80, 256, 0, stream>>>(M_MEAN, mos, Q);

  // --- etf -> v_et (masked mean over L=128), CH=4 (32 rows each) ---
  mean_partial_k<<<512 * 4, 192, 0, stream>>>(etf, etm, PART, MSUM, 128, 4, 32);
  mean_combine_k<<<384, 256, 0, stream>>>(PART, MSUM, V_ET, 512, 4, 0.f);

  // --- mtet (needs etf CLS + m_span) ---
  mtet_k<<<128, 256, 0, stream>>>(etf, M_SPAN, MTET);

  // --- eif -> v_ei (mean over P=196), CH=7 (28 rows each) ---
  mean_partial_k<<<512 * 7, 192, 0, stream>>>(eif, nullptr, PART, nullptr, 196, 7, 28);
  mean_combine_k<<<384, 256, 0, stream>>>(PART, nullptr, V_EI, 512, 7, 1.f / 196.f);

  // --- eof fused reduce+normalize+dot -> p ---
  eof_dot_k<<<32 * 16 * 5, 128, 0, stream>>>(eofp, M_MEAN, Q, eos, P_BUF);

  // --- miei ---
  miei_k<<<2, 256, 0, stream>>>(P_BUF, mos, eos, MIEI);

  // --- GCN collapsed ---
  gcn_k<<<96, 256, 0, stream>>>(V_MT, V_MI, V_ET, V_EI, MTET, mtei, miet, MIEI,
                                MENTION, S_ARR);

  // --- final cosine ---
  final_k<<<128, 256, 0, stream>>>(MENTION, S_ARR, V_ET, out);
}

// Round 2
// 229.741 us; speedup vs baseline: 1.1351x; 1.1351x over previous
//
#include <hip/hip_runtime.h>

#define EPSF 1e-8f

// Dimensions (compile-time constants)
#define B_  32
#define C_  16
#define L_  128
#define D_  768
#define D4_ 192   // D/4
#define P_  196
#define OM_ 10
#define OE_ 10
#define R_  36

// ---------- small helpers ----------
__device__ __forceinline__ float4 f4add(float4 a, float4 b){
  return make_float4(a.x+b.x, a.y+b.y, a.z+b.z, a.w+b.w);
}
__device__ __forceinline__ float4 f4scale(float4 a, float s){
  return make_float4(a.x*s, a.y*s, a.z*s, a.w*s);
}
__device__ __forceinline__ float f4dot(float4 a, float4 b){
  return a.x*b.x + a.y*b.y + a.z*b.z + a.w*b.w;
}
__device__ __forceinline__ float wave_sum(float v){
  #pragma unroll
  for (int off = 32; off > 0; off >>= 1) v += __shfl_down(v, off);
  return v;  // valid on lane 0
}

// ================= K1: all split-K mean partials, one dispatch =================
// Section table (block ranges, big first):
//   [0,3584)    eif: N=512, ROWS=196, CH=7, RPC=28
//   [3584,5632) etf: N=512, ROWS=128, CH=4, RPC=32, mask=etm, msum base 128
//   [5632,6272) mof: N=320, ROWS=36,  CH=2, RPC=18
//   [6272,6496) mif: N=32,  ROWS=196, CH=7, RPC=28
//   [6496,6624) mtf: N=32,  ROWS=128, CH=4, RPC=32, mask=mtm, msum base 0
__global__ __launch_bounds__(192)
void means_k(const float* __restrict__ eif, const float* __restrict__ etf,
             const float* __restrict__ mof, const float* __restrict__ mif,
             const float* __restrict__ mtf,
             const float* __restrict__ etm, const float* __restrict__ mtm,
             float* __restrict__ part_eif, float* __restrict__ part_etf,
             float* __restrict__ part_mof, float* __restrict__ part_mif,
             float* __restrict__ part_mtf, float* __restrict__ msum)
{
  int blk = blockIdx.x;
  const float* in; const float* mask = nullptr;
  float* part; float* ms = nullptr;
  int ROWS, CH, RPC;
  if (blk < 3584)      { in = eif; part = part_eif; ROWS = 196; CH = 7; RPC = 28; }
  else if (blk < 5632) { blk -= 3584; in = etf; mask = etm; ms = msum + 128;
                         part = part_etf; ROWS = 128; CH = 4; RPC = 32; }
  else if (blk < 6272) { blk -= 5632; in = mof; part = part_mof; ROWS = 36; CH = 2; RPC = 18; }
  else if (blk < 6496) { blk -= 6272; in = mif; part = part_mif; ROWS = 196; CH = 7; RPC = 28; }
  else                 { blk -= 6496; in = mtf; mask = mtm; ms = msum;
                         part = part_mtf; ROWS = 128; CH = 4; RPC = 32; }

  int g = blk / CH, ch = blk - g * CH;
  int r0 = ch * RPC;
  int r1 = r0 + RPC; if (r1 > ROWS) r1 = ROWS;
  int t = threadIdx.x;
  const float4* inp = (const float4*)in + (size_t)g * ROWS * D4_;
  float4 acc = make_float4(0.f, 0.f, 0.f, 0.f);
  if (mask) {
    const float* mrow = mask + (size_t)g * ROWS;
    float msacc = 0.f;
    #pragma unroll 4
    for (int r = r0; r < r1; ++r) {
      float w = mrow[r];
      float4 v = inp[(size_t)r * D4_ + t];
      acc.x += v.x * w; acc.y += v.y * w; acc.z += v.z * w; acc.w += v.w * w;
      msacc += w;
    }
    if (t == 0) ms[blk] = msacc;
  } else {
    #pragma unroll 4
    for (int r = r0; r < r1; ++r)
      acc = f4add(acc, inp[(size_t)r * D4_ + t]);
  }
  ((float4*)part)[(size_t)blk * D4_ + t] = acc;
}

// ================= K2: all combines + norm_q + mtet, one dispatch =================
// Block ranges (256 threads each):
//   [0,384)      v_ei combine  (N=512, CH=7, 1/196)
//   [384,768)    v_et combine  (N=512, CH=4, masked, msum+128)
//   [768,1008)   m_mean combine(N=320, CH=2, 1/36)
//   [1008,1032)  v_mi combine  (N=32,  CH=7, 1/196)
//   [1032,1056)  v_mt combine  (N=32,  CH=4, masked, msum+0)
//   [1056,1136)  norm_q: 320 waves over part_mof
//   [1136,1264)  mtet: 512 waves, span inlined from mtf
__device__ __forceinline__ void combine_body(const float* __restrict__ part,
                                             const float* __restrict__ msum,
                                             float* __restrict__ out,
                                             int secblk, int CH, float invn)
{
  int idx = secblk * 256 + threadIdx.x;      // f4 index into out
  int g = idx / D4_, t = idx - g * D4_;
  const float4* pp = (const float4*)part + (size_t)(g * CH) * D4_ + t;
  float4 acc = make_float4(0.f, 0.f, 0.f, 0.f);
  for (int ch = 0; ch < CH; ++ch) acc = f4add(acc, pp[(size_t)ch * D4_]);
  float scale;
  if (msum) {
    float s = 0.f;
    for (int ch = 0; ch < CH; ++ch) s += msum[g * CH + ch];
    scale = 1.f / fmaxf(s, 1.f);
  } else scale = invn;
  ((float4*)out)[idx] = f4scale(acc, scale);
}

__global__ __launch_bounds__(256)
void combine_k(const float* __restrict__ part_eif, const float* __restrict__ part_etf,
               const float* __restrict__ part_mof, const float* __restrict__ part_mif,
               const float* __restrict__ part_mtf, const float* __restrict__ msum,
               const float* __restrict__ etf, const float* __restrict__ mtf,
               const int* __restrict__ msp, const int* __restrict__ mep,
               const float* __restrict__ mos,
               float* __restrict__ v_ei, float* __restrict__ v_et,
               float* __restrict__ m_mean, float* __restrict__ v_mi,
               float* __restrict__ v_mt, float* __restrict__ q,
               float* __restrict__ mtet)
{
  int blk = blockIdx.x;
  if (blk < 384)       { combine_body(part_eif, nullptr, v_ei, blk, 7, 1.f/196.f); return; }
  else if (blk < 768)  { combine_body(part_etf, msum + 128, v_et, blk - 384, 4, 0.f); return; }
  else if (blk < 1008) { combine_body(part_mof, nullptr, m_mean, blk - 768, 2, 1.f/36.f); return; }
  else if (blk < 1032) { combine_body(part_mif, nullptr, v_mi, blk - 1008, 7, 1.f/196.f); return; }
  else if (blk < 1056) { combine_body(part_mtf, msum, v_mt, blk - 1032, 4, 0.f); return; }
  else if (blk < 1136) {
    // norm_q: q[w] = mos[w] / max(|m_mean[w]|, eps), from part_mof directly
    int w = (blk - 1056) * 4 + (threadIdx.x >> 6);       // [0,320)
    int lane = threadIdx.x & 63;
    const float4* pm = (const float4*)part_mof + (size_t)(w * 2) * D4_;
    const float inv36 = 1.f / 36.f;
    float n = 0.f;
    #pragma unroll
    for (int k = 0; k < 3; ++k) {
      float4 v = f4scale(f4add(pm[lane + 64*k], pm[(size_t)D4_ + lane + 64*k]), inv36);
      n += f4dot(v, v);
    }
    n = wave_sum(n);
    if (lane == 0) q[w] = mos[w] / fmaxf(sqrtf(n), EPSF);
    return;
  } else {
    // mtet: wave per (b,c); span gathered inline
    int w = (blk - 1136) * 4 + (threadIdx.x >> 6);       // [0,512)
    int lane = threadIdx.x & 63;
    int b = w >> 4;
    const float4* ecls = (const float4*)etf + (size_t)w * L_ * D4_;  // l = 0
    const float4* mb   = (const float4*)mtf + (size_t)b * L_ * D4_;
    int sp = msp[b], ep = mep[b];
    float dt = 0.f, na = 0.f, nb = 0.f;
    #pragma unroll
    for (int k = 0; k < 3; ++k) {
      float4 a = f4scale(f4add(mb[(size_t)sp * D4_ + lane + 64*k],
                               mb[(size_t)ep * D4_ + lane + 64*k]), 0.5f);
      float4 e = ecls[lane + 64*k];
      dt += f4dot(a, e); na += f4dot(a, a); nb += f4dot(e, e);
    }
    dt = wave_sum(dt); na = wave_sum(na); nb = wave_sum(nb);
    if (lane == 0) mtet[w] = dt / fmaxf(sqrtf(na) * sqrtf(nb), EPSF);
  }
}

// ================= K3: eof fused mean+norm+dot =================
// grid: B*C*5 blocks x 128 threads (2 waves, wave handles j = jp*2+waveid)
// p[b,c,j] = eos * (1/max(|e|,eps)) * sum_i q[b,i]*(m[b,i]·e[b,c,j])
__global__ __launch_bounds__(128)
void eof_dot_k(const float* __restrict__ eof, const float* __restrict__ m_mean,
               const float* __restrict__ q, const float* __restrict__ eos,
               float* __restrict__ p)
{
  int blk = blockIdx.x;          // (b*C + c)*5 + jp
  int bc = blk / 5, jp = blk - bc * 5;
  int b = bc / C_;
  int wave = threadIdx.x >> 6, lane = threadIdx.x & 63;
  int j = jp * 2 + wave;
  size_t g = (size_t)bc * OE_ + j;
  const float4* ep = (const float4*)eof + g * R_ * D4_;
  float4 a0 = make_float4(0,0,0,0), a1 = a0, a2 = a0;
  #pragma unroll 4
  for (int r = 0; r < R_; ++r) {
    const float4* row = ep + (size_t)r * D4_;
    a0 = f4add(a0, row[lane]);
    a1 = f4add(a1, row[lane + 64]);
    a2 = f4add(a2, row[lane + 128]);
  }
  const float inv36 = 1.f / 36.f;
  a0 = f4scale(a0, inv36); a1 = f4scale(a1, inv36); a2 = f4scale(a2, inv36);
  float nrm = f4dot(a0, a0) + f4dot(a1, a1) + f4dot(a2, a2);
  float s = 0.f;
  const float4* mp = (const float4*)m_mean + (size_t)b * OM_ * D4_;
  #pragma unroll
  for (int i = 0; i < OM_; ++i) {
    const float4* mr = mp + (size_t)i * D4_;
    float di = f4dot(a0, mr[lane]) + f4dot(a1, mr[lane + 64]) + f4dot(a2, mr[lane + 128]);
    s += q[b * OM_ + i] * di;
  }
  s = wave_sum(s); nrm = wave_sum(nrm);
  if (lane == 0) {
    float einv = 1.f / fmaxf(sqrtf(nrm), EPSF);
    p[g] = eos[g] * s * einv;
  }
}

// ================= K4: miei + collapsed GCN + final cosine, one block per b =================
__global__ __launch_bounds__(256)
void tail_k(const float* __restrict__ p, const float* __restrict__ mos,
            const float* __restrict__ eos,
            const float* __restrict__ v_mt, const float* __restrict__ v_mi,
            const float* __restrict__ v_et, const float* __restrict__ v_ei,
            const float* __restrict__ mtet, const float* __restrict__ mtei,
            const float* __restrict__ miet,
            float* __restrict__ out)
{
  __shared__ float sh_e0[C_], sh_e1[C_], sh_e2[C_], sh_e3[C_];
  __shared__ float4 sh_m4[D4_], sh_s4[D4_];
  int b = blockIdx.x, tid = threadIdx.x;

  if (tid < C_) {
    int bc = b * C_ + tid;
    float num = 0.f, se = 0.f, sm = 0.f;
    #pragma unroll
    for (int j = 0; j < OE_; ++j) { num += p[bc * OE_ + j]; se += eos[bc * OE_ + j]; }
    #pragma unroll
    for (int i = 0; i < OM_; ++i) sm += mos[b * OM_ + i];
    sh_e3[tid] = num / (sm * se);      // miei
    sh_e0[tid] = mtet[bc];
    sh_e1[tid] = mtei[bc];
    sh_e2[tid] = miet[bc];
  }
  __syncthreads();

  const float invC = 1.f / (float)C_;
  for (int d = tid; d < D_; d += 256) {
    float vmt = v_mt[b * D_ + d], vmi = v_mi[b * D_ + d];
    float nv0 = 0.f, nv1 = 0.f, macc = 0.f;
    #pragma unroll
    for (int c = 0; c < C_; ++c) {
      int bc = b * C_ + c;
      float et = v_et[(size_t)bc * D_ + d];
      float ei = v_ei[(size_t)bc * D_ + d];
      float e0 = sh_e0[c], e1 = sh_e1[c], e2 = sh_e2[c], e3 = sh_e3[c];
      nv0 += e0 * et + e1 * ei;
      nv1 += e2 * et + e3 * ei;
      macc += (vmt * et) * (e0 * vmt + e2 * vmi)
            + (vmt * ei) * (e1 * vmt + e3 * vmi);
    }
    ((float*)sh_m4)[d] = macc * invC;
    ((float*)sh_s4)[d] = vmt * (nv0 * invC) + vmi * (nv1 * invC);
  }
  __syncthreads();

  int wv = tid >> 6, lane = tid & 63;
  for (int c = wv; c < C_; c += 4) {
    const float4* ep = (const float4*)v_et + (size_t)(b * C_ + c) * D4_;
    float dt = 0.f, nm = 0.f, ne = 0.f;
    #pragma unroll
    for (int k = 0; k < 3; ++k) {
      float4 m = sh_m4[lane + 64*k];
      float4 sv = sh_s4[lane + 64*k];
      float4 e = ep[lane + 64*k];
      float4 ent = make_float4(e.x * sv.x, e.y * sv.y, e.z * sv.z, e.w * sv.w);
      dt += f4dot(m, ent); nm += f4dot(m, m); ne += f4dot(ent, ent);
    }
    dt = wave_sum(dt); nm = wave_sum(nm); ne = wave_sum(ne);
    if (lane == 0) out[b * C_ + c] = dt / fmaxf(sqrtf(nm) * sqrtf(ne), EPSF);
  }
}

extern "C" void kernel_launch(void* const* d_in, const int* in_sizes, int n_in,
                              void* d_out, int out_size, void* d_ws, size_t ws_size,
                              hipStream_t stream)
{
  const float* mtf  = (const float*)d_in[0];
  const float* mtm  = (const float*)d_in[1];
  const int*   msp  = (const int*)  d_in[2];
  const int*   mep  = (const int*)  d_in[3];
  const float* mif  = (const float*)d_in[4];
  const float* mof  = (const float*)d_in[5];
  const float* mos  = (const float*)d_in[6];
  const float* etf  = (const float*)d_in[7];
  const float* etm  = (const float*)d_in[8];
  const float* eif  = (const float*)d_in[9];
  const float* eofp = (const float*)d_in[10];
  const float* eos  = (const float*)d_in[11];
  const float* miet = (const float*)d_in[12];
  const float* mtei = (const float*)d_in[13];
  float* out = (float*)d_out;
  float* ws = (float*)d_ws;

  // workspace layout (floats), all regions f4-aligned
  float* PART_EIF = ws;                       // 3584*768 = 2752512
  float* PART_ETF = PART_EIF + 2752512;       // 2048*768 = 1572864
  float* PART_MOF = PART_ETF + 1572864;       //  640*768 =  491520
  float* PART_MIF = PART_MOF + 491520;        //  224*768 =  172032
  float* PART_MTF = PART_MIF + 172032;        //  128*768 =   98304
  float* MSUM     = PART_MTF + 98304;         // 2560 (mtf@0:128, etf@128:2048)
  float* V_MT     = MSUM     + 2560;          // 24576
  float* V_MI     = V_MT     + 24576;         // 24576
  float* V_ET     = V_MI     + 24576;         // 393216
  float* V_EI     = V_ET     + 393216;        // 393216
  float* M_MEAN   = V_EI     + 393216;        // 245760
  float* Q        = M_MEAN   + 245760;        // 512
  float* MTET     = Q        + 512;           // 512
  float* P_BUF    = MTET     + 512;           // 5120

  // K1: all mean partials (eif, etf, mof, mif, mtf)
  means_k<<<6624, 192, 0, stream>>>(eif, etf, mof, mif, mtf, etm, mtm,
                                    PART_EIF, PART_ETF, PART_MOF, PART_MIF,
                                    PART_MTF, MSUM);

  // K2: combines + norm_q + mtet(span inline)
  combine_k<<<1264, 256, 0, stream>>>(PART_EIF, PART_ETF, PART_MOF, PART_MIF,
                                      PART_MTF, MSUM, etf, mtf, msp, mep, mos,
                                      V_EI, V_ET, M_MEAN, V_MI, V_MT, Q, MTET);

  // K3: eof fused reduce+normalize+dot -> p
  eof_dot_k<<<B_ * C_ * 5, 128, 0, stream>>>(eofp, M_MEAN, Q, eos, P_BUF);

  // K4: miei + GCN + final cosine
  tail_k<<<B_, 256, 0, stream>>>(P_BUF, mos, eos, V_MT, V_MI, V_ET, V_EI,
                                 MTET, mtei, miet, out);
}